// Round 7
// baseline (102.118 us; speedup 1.0000x reference)
//
#include <hip/hip_runtime.h>
#include <hip/hip_bf16.h>
#include <math.h>

// Dempster-Shafer evidential forward — fused single kernel (R7).
//   input [B,C,H,W,D] f32, W [K,C], BETA [K,M], alpha [K,1], gamma [K,1]
//   out   [B,M+1,H,W,D] f32;  K=20, C=16, M=4, B=2.
//
// Closed form (R4): P_m = prod_k (1 - c_m[k]*e_k), O = prod_k (1 - a_k*e_k),
//   e_k = 2^arg_k, arg_k = dot(x, g^2*log2e*W_k) - 0.5*g^2*log2e*(||x||^2+||W_k||^2).
// Dot via v_mfma_f32_32x32x16_bf16: A=Wp[32 protos x 16 ch], B=X[16 ch x 32 elems];
// C/D col=lane&31=elem, row=(r&3)+8*(r>>2)+4*half=proto; wave halves hold disjoint
// proto subsets, merged by shfl_xor(32). Bias folded via rank-2 second MFMA.
// (Verified R5/R6, absmax 3.9e-3.)
//
// R7 vs R6: the load path. R4/R5/R6 all plateaued at kernel ~17-22us ~= 2.5 TB/s
// achieved BW with 4B/lane dword loads; the 6.3 TB/s ceiling (m13) needs 16B/lane.
// Now: 8x global_load_dwordx4 per wave stage 128 elems x 16 ch (1KB/instr, each =
// 2 channels x 512B contiguous), transposed to MFMA B-layout via a wave-private
// LDS tile [16][132] (reads conflict-free; half-alias 2-way = free). Loads issue
// before the constant-prep + __syncthreads so HBM latency overlaps prep.
#define NK 20
#define NC 16
#define NM 4
#define LDSW 132   // padded row stride (floats)

typedef __attribute__((ext_vector_type(8)))  short  short8;
typedef __attribute__((ext_vector_type(16))) float  floatx16;

static __device__ __forceinline__ short bf16b(float f) {
    __hip_bfloat16 h = __float2bfloat16(f);
    return *reinterpret_cast<short*>(&h);
}

__global__ __launch_bounds__(256, 4) void ds_fused(
    const float* __restrict__ inp,
    const float* __restrict__ Wg,
    const float* __restrict__ BETAg,
    const float* __restrict__ alphag,
    const float* __restrict__ gammag,
    float* __restrict__ out,
    int S,        // H*W*D = 262144
    int BS)       // B*S
{
    __shared__ __align__(16) float sCst[32][8];    // {c0,c1,c2,c3,a,0,0,0} per proto
    __shared__ __align__(16) short sWpb[32][16];   // bf16(g2L*W), rows 20..31 zero
    __shared__ short sA2[32][2];                   // bf16{nh, nbk}
    __shared__ __align__(16) float sX[4][NC][LDSW];// per-wave staging tile

    const int t    = threadIdx.x;
    const int lane = t & 63;
    const int half = lane >> 5;
    const int col  = lane & 31;
    const int w    = t >> 6;

    // wave's 128-element span; grid covers BS exactly, S % 128 == 0 -> b uniform
    const int ebase = (blockIdx.x * 4 + w) * 128;
    const int b     = (ebase >= S) ? 1 : 0;
    const int spw   = ebase - b * S;
    const float* xb = inp + (size_t)b * NC * S + spw;

    // ---- 1) issue ALL global loads first (overlap with prep below)
    float4 xv[8];
    #pragma unroll
    for (int cc = 0; cc < 8; ++cc) {
        const int ch = 2*cc + half;                  // 2 channels per instruction
        xv[cc] = *(const float4*)(xb + (size_t)ch * S + 4*col);
    }

    // ---- 2) derived constants into LDS (threads 0..31)
    if (t < 32) {
        if (t < NK) {
            const float L   = 1.4426950408889634f;   // log2(e)
            const float g   = gammag[t];
            const float g2L = g * g * L;
            float w2 = 0.f;
            #pragma unroll
            for (int c = 0; c < NC; ++c) {
                const float wv = Wg[t*NC + c];
                sWpb[t][c] = bf16b(g2L * wv);
                w2 = fmaf(wv, wv, w2);
            }
            const float a = 0.99f / (1.0f + __expf(-alphag[t]));
            float b0 = BETAg[t*NM+0], b1 = BETAg[t*NM+1], b2 = BETAg[t*NM+2], b3 = BETAg[t*NM+3];
            b0 *= b0; b1 *= b1; b2 *= b2; b3 *= b3;
            const float uinv = 1.0f / (b0 + b1 + b2 + b3);
            sCst[t][0] = (1.0f - b0*uinv) * a;
            sCst[t][1] = (1.0f - b1*uinv) * a;
            sCst[t][2] = (1.0f - b2*uinv) * a;
            sCst[t][3] = (1.0f - b3*uinv) * a;
            sCst[t][4] = a;
            sCst[t][5] = 0.f; sCst[t][6] = 0.f; sCst[t][7] = 0.f;
            sA2[t][0] = bf16b(-0.5f * g2L);
            sA2[t][1] = bf16b(-0.5f * g2L * w2);
        } else {
            #pragma unroll
            for (int i = 0; i < 8; ++i) sCst[t][i] = 0.f;
            #pragma unroll
            for (int c = 0; c < NC; ++c) sWpb[t][c] = 0;
            sA2[t][0] = 0; sA2[t][1] = 0;
        }
    }
    __syncthreads();

    // ---- 3) stage input to wave-private LDS tile (transpose for B-frag reads)
    #pragma unroll
    for (int cc = 0; cc < 8; ++cc) {
        const int ch = 2*cc + half;
        *(float4*)&sX[w][ch][4*col] = xv[cc];
    }
    // wave-private region: compiler-inserted lgkmcnt orders read-after-write.

    // ---- 4) wave-invariant fragments / per-lane chain constants
    const short8 afrag = *(const short8*)&sWpb[col][half*8];
    short8 a2frag;
    #pragma unroll
    for (int j = 0; j < 8; ++j) a2frag[j] = 0;
    if (half == 0) { a2frag[0] = sA2[col][0]; a2frag[1] = sA2[col][1]; }

    float cm0[12], cm1[12], cm2[12], cm3[12], cO[12];
    #pragma unroll
    for (int r = 0; r < 12; ++r) {
        const int p = (r & 3) + 8*(r >> 2) + 4*half;
        const float4 cv = *(const float4*)&sCst[p][0];
        cm0[r] = cv.x; cm1[r] = cv.y; cm2[r] = cv.z; cm3[r] = cv.w;
        cO[r]  = sCst[p][4];
    }

    float* ob = out + (size_t)b * (NM+1) * S + spw;

    // ---- 5) four 32-element tiles
    #pragma unroll
    for (int tt = 0; tt < 4; ++tt) {
        short8 bfrag;
        float x2p = 0.f;
        #pragma unroll
        for (int j = 0; j < 8; ++j) {
            const float v = sX[w][8*half + j][tt*32 + col];
            x2p = fmaf(v, v, x2p);
            bfrag[j] = bf16b(v);
        }
        const float x2 = x2p + __shfl_xor(x2p, 32, 64);

        short8 b2frag;
        #pragma unroll
        for (int j = 0; j < 8; ++j) b2frag[j] = 0;
        if (half == 0) { b2frag[0] = bf16b(x2); b2frag[1] = (short)0x3F80; }  // [x2, 1]

        floatx16 acc;
        #pragma unroll
        for (int i = 0; i < 16; ++i) acc[i] = 0.f;
        acc = __builtin_amdgcn_mfma_f32_32x32x16_bf16(afrag,  bfrag,  acc, 0, 0, 0);
        acc = __builtin_amdgcn_mfma_f32_32x32x16_bf16(a2frag, b2frag, acc, 0, 0, 0);

        float P0 = 1.f, P1 = 1.f, P2 = 1.f, P3 = 1.f, PO = 1.f;
        #pragma unroll
        for (int r = 0; r < 12; ++r) {
            const float ek = __builtin_amdgcn_exp2f(acc[r]);
            P0 *= fmaf(-cm0[r], ek, 1.0f);
            P1 *= fmaf(-cm1[r], ek, 1.0f);
            P2 *= fmaf(-cm2[r], ek, 1.0f);
            P3 *= fmaf(-cm3[r], ek, 1.0f);
            PO *= fmaf(-cO[r],  ek, 1.0f);
        }
        P0 *= __shfl_xor(P0, 32, 64);
        P1 *= __shfl_xor(P1, 32, 64);
        P2 *= __shfl_xor(P2, 32, 64);
        P3 *= __shfl_xor(P3, 32, 64);
        PO *= __shfl_xor(PO, 32, 64);

        const float O  = PO;
        const float f0 = P0 - O, f1 = P1 - O, f2 = P2 - O, f3 = P3 - O;
        const float inv = 1.0f / (f0 + f1 + f2 + f3 + O);

        float* op = ob + tt*32 + col;
        if (half == 0) {
            op[0]           = f0 * inv;
            op[(size_t)S]   = f1 * inv;
            op[(size_t)2*S] = f2 * inv;
        } else {
            op[(size_t)3*S] = f3 * inv;
            op[(size_t)4*S] = O  * inv;
        }
    }
}

extern "C" void kernel_launch(void* const* d_in, const int* in_sizes, int n_in,
                              void* d_out, int out_size, void* d_ws, size_t ws_size,
                              hipStream_t stream) {
    const float* inp   = (const float*)d_in[0];
    const float* Wg    = (const float*)d_in[1];
    const float* BETAg = (const float*)d_in[2];
    const float* alphag= (const float*)d_in[3];
    const float* gammag= (const float*)d_in[4];
    float* out = (float*)d_out;

    const int BS = in_sizes[0] / NC;   // B*S = 524288
    const int S  = BS / 2;             // 262144 (B=2 fixed by setup_inputs)

    // one wave covers 128 elems; 4 waves/block -> 512 elems/block
    const int grid = BS / 512;         // 1024, exact
    ds_fused<<<grid, 256, 0, stream>>>(inp, Wg, BETAg, alphag, gammag, out, S, BS);
}

// Round 8
// 87.429 us; speedup vs baseline: 1.1680x; 1.1680x over previous
//
#include <hip/hip_runtime.h>
#include <hip/hip_bf16.h>
#include <math.h>

// Dempster-Shafer evidential forward — fused single kernel (R8).
//   input [B,C,H,W,D] f32, W [K,C], BETA [K,M], alpha [K,1], gamma [K,1]
//   out   [B,M+1,H,W,D] f32;  K=20, C=16, M=4, B=2.
//
// Closed form (R4): P_m = prod_k (1 - c_m[k]*e_k), O = prod_k (1 - a_k*e_k),
//   e_k = 2^arg_k, arg_k = dot(x, g^2*log2e*W_k) - 0.5*g^2*log2e*(||x||^2+||W_k||^2).
// Dot via v_mfma_f32_32x32x16_bf16: A=Wp[32 protos x 16 ch], B=X[16 ch x 32 elems];
// C/D col=lane&31=elem, row=(r&3)+8*(r>>2)+4*half=proto; wave halves hold disjoint
// proto subsets, merged by shfl_xor(32). Bias folded via rank-2 second MFMA.
//
// R8 = R6 structure (direct global->reg loads; R7's LDS-transpose convoy REGRESSED
// 17->33us and falsified the load-width/BW theory) with duty-cycle fixes:
//  - TSTEP=4: 32 hoisted dword loads/wave, fine-grained vmcnt waits pipeline
//    tiles 1-3's arrival under tile 0-2's compute; wave-startup (constant
//    ds_reads + barrier drain) amortized over 128 elems (2x R6).
//  - cO regs eliminated: sum_m c_m = 3a  =>  cO = (c0+c1+c2+c3)/3 (zero rows
//    stay zero, so dummy protos 20..31 still contribute factor 1). Keeps
//    VGPR ~<=128 at 4 waves/EU, no spill.
#define NK 20
#define NC 16
#define NM 4
#define TSTEP 4

typedef __attribute__((ext_vector_type(8)))  short  short8;
typedef __attribute__((ext_vector_type(16))) float  floatx16;

static __device__ __forceinline__ short bf16b(float f) {
    __hip_bfloat16 h = __float2bfloat16(f);
    return *reinterpret_cast<short*>(&h);
}

__global__ __launch_bounds__(256, 4) void ds_fused(
    const float* __restrict__ inp,
    const float* __restrict__ Wg,
    const float* __restrict__ BETAg,
    const float* __restrict__ alphag,
    const float* __restrict__ gammag,
    float* __restrict__ out,
    int S,        // H*W*D = 262144
    int BS)       // B*S
{
    __shared__ __align__(16) float sCst[32][8];   // {c0,c1,c2,c3,a,0,0,0} per proto
    __shared__ __align__(16) short sWpb[32][16];  // bf16(g2L*W), rows 20..31 zero
    __shared__ short sA2[32][2];                  // bf16{nh, nbk}

    const int t    = threadIdx.x;
    const int lane = t & 63;
    const int half = lane >> 5;
    const int col  = lane & 31;

    // wave's 128-element span; grid covers BS exactly, S % 128 == 0 -> b uniform
    const int ebase = (blockIdx.x * 4 + (t >> 6)) * (TSTEP * 32);
    const int b     = (ebase >= S) ? 1 : 0;
    const int spw   = ebase - b * S;
    const float* xb = inp + (size_t)b * NC * S + spw + col;

    // ---- 1) hoist ALL tile loads (32 dwords/lane-group; latency overlaps prep)
    float xv[TSTEP][8];
    #pragma unroll
    for (int tt = 0; tt < TSTEP; ++tt)
        #pragma unroll
        for (int j = 0; j < 8; ++j)
            xv[tt][j] = xb[(size_t)(8*half + j) * S + tt*32];

    // ---- 2) derived constants into LDS (threads 0..31 of wave 0)
    if (t < 32) {
        if (t < NK) {
            const float L   = 1.4426950408889634f;   // log2(e)
            const float g   = gammag[t];
            const float g2L = g * g * L;
            float w2 = 0.f;
            #pragma unroll
            for (int c = 0; c < NC; ++c) {
                const float wv = Wg[t*NC + c];
                sWpb[t][c] = bf16b(g2L * wv);
                w2 = fmaf(wv, wv, w2);
            }
            const float a = 0.99f / (1.0f + __expf(-alphag[t]));
            float b0 = BETAg[t*NM+0], b1 = BETAg[t*NM+1], b2 = BETAg[t*NM+2], b3 = BETAg[t*NM+3];
            b0 *= b0; b1 *= b1; b2 *= b2; b3 *= b3;
            const float uinv = 1.0f / (b0 + b1 + b2 + b3);
            sCst[t][0] = (1.0f - b0*uinv) * a;
            sCst[t][1] = (1.0f - b1*uinv) * a;
            sCst[t][2] = (1.0f - b2*uinv) * a;
            sCst[t][3] = (1.0f - b3*uinv) * a;
            sCst[t][4] = a;
            sCst[t][5] = 0.f; sCst[t][6] = 0.f; sCst[t][7] = 0.f;
            sA2[t][0] = bf16b(-0.5f * g2L);
            sA2[t][1] = bf16b(-0.5f * g2L * w2);
        } else {
            #pragma unroll
            for (int i = 0; i < 8; ++i) sCst[t][i] = 0.f;
            #pragma unroll
            for (int c = 0; c < NC; ++c) sWpb[t][c] = 0;
            sA2[t][0] = 0; sA2[t][1] = 0;
        }
    }
    __syncthreads();

    // ---- 3) wave-invariant fragments / per-lane chain constants
    const short8 afrag = *(const short8*)&sWpb[col][half*8];
    short8 a2frag;
    #pragma unroll
    for (int j = 0; j < 8; ++j) a2frag[j] = 0;
    if (half == 0) { a2frag[0] = sA2[col][0]; a2frag[1] = sA2[col][1]; }

    float4 cm[12];
    #pragma unroll
    for (int r = 0; r < 12; ++r) {
        const int p = (r & 3) + 8*(r >> 2) + 4*half;
        cm[r] = *(const float4*)&sCst[p][0];
    }

    short8 b2base;                                 // invariant part of B2
    #pragma unroll
    for (int j = 0; j < 8; ++j) b2base[j] = 0;
    if (half == 0) b2base[1] = (short)0x3F80;      // 1.0f (bf16)

    float* ob = out + (size_t)b * (NM+1) * S + spw + col;

    // ---- 4) four 32-element tiles (unrolled; vmcnt waits are fine-grained)
    #pragma unroll
    for (int tt = 0; tt < TSTEP; ++tt) {
        short8 bfrag;
        float x2p = 0.f;
        #pragma unroll
        for (int j = 0; j < 8; ++j) {
            const float v = xv[tt][j];
            x2p = fmaf(v, v, x2p);
            bfrag[j] = bf16b(v);
        }
        const float x2 = x2p + __shfl_xor(x2p, 32, 64);

        short8 b2frag = b2base;
        if (half == 0) b2frag[0] = bf16b(x2);

        floatx16 acc;
        #pragma unroll
        for (int i = 0; i < 16; ++i) acc[i] = 0.f;
        acc = __builtin_amdgcn_mfma_f32_32x32x16_bf16(afrag,  bfrag,  acc, 0, 0, 0);
        acc = __builtin_amdgcn_mfma_f32_32x32x16_bf16(a2frag, b2frag, acc, 0, 0, 0);

        float P0 = 1.f, P1 = 1.f, P2 = 1.f, P3 = 1.f, PO = 1.f;
        #pragma unroll
        for (int r = 0; r < 12; ++r) {
            const float ek = __builtin_amdgcn_exp2f(acc[r]);
            const float cO = (cm[r].x + cm[r].y + cm[r].z + cm[r].w) * (1.0f/3.0f);
            P0 *= fmaf(-cm[r].x, ek, 1.0f);
            P1 *= fmaf(-cm[r].y, ek, 1.0f);
            P2 *= fmaf(-cm[r].z, ek, 1.0f);
            P3 *= fmaf(-cm[r].w, ek, 1.0f);
            PO *= fmaf(-cO,      ek, 1.0f);
        }
        // merge the halves' disjoint proto subsets
        P0 *= __shfl_xor(P0, 32, 64);
        P1 *= __shfl_xor(P1, 32, 64);
        P2 *= __shfl_xor(P2, 32, 64);
        P3 *= __shfl_xor(P3, 32, 64);
        PO *= __shfl_xor(PO, 32, 64);

        const float O  = PO;
        const float f0 = P0 - O, f1 = P1 - O, f2 = P2 - O, f3 = P3 - O;
        const float inv = 1.0f / (f0 + f1 + f2 + f3 + O);

        float* op = ob + tt*32;
        if (half == 0) {
            op[0]           = f0 * inv;
            op[(size_t)S]   = f1 * inv;
            op[(size_t)2*S] = f2 * inv;
        } else {
            op[(size_t)3*S] = f3 * inv;
            op[(size_t)4*S] = O  * inv;
        }
    }
}

extern "C" void kernel_launch(void* const* d_in, const int* in_sizes, int n_in,
                              void* d_out, int out_size, void* d_ws, size_t ws_size,
                              hipStream_t stream) {
    const float* inp   = (const float*)d_in[0];
    const float* Wg    = (const float*)d_in[1];
    const float* BETAg = (const float*)d_in[2];
    const float* alphag= (const float*)d_in[3];
    const float* gammag= (const float*)d_in[4];
    float* out = (float*)d_out;

    const int BS = in_sizes[0] / NC;   // B*S = 524288
    const int S  = BS / 2;             // 262144 (B=2 fixed by setup_inputs)

    // one wave covers TSTEP*32 = 128 elems; 4 waves/block -> 512 elems/block
    const int grid = BS / 512;         // 1024, exact
    ds_fused<<<grid, 256, 0, stream>>>(inp, Wg, BETAg, alphag, gammag, out, S, BS);
}